// Round 5
// baseline (1180.667 us; speedup 1.0000x reference)
//
#include <hip/hip_runtime.h>
#include <hip/hip_bf16.h>
#include <math.h>

typedef __attribute__((ext_vector_type(8))) short bf8_t;   // 8 x bf16 (4 VGPRs)
typedef __attribute__((ext_vector_type(4))) float f4_t;    // MFMA accumulator
typedef __attribute__((ext_vector_type(8))) unsigned short us8_t;

__device__ inline unsigned short f2bf(float f) {
  union { float f; unsigned u; } x; x.f = f;
  unsigned r = x.u + 0x7FFF + ((x.u >> 16) & 1);   // RNE
  return (unsigned short)(r >> 16);
}
__device__ inline float bflo(unsigned v) {
  union { unsigned u; float f; } x; x.u = v << 16; return x.f;
}
__device__ inline float bfhi(unsigned v) {
  union { unsigned u; float f; } x; x.u = v & 0xFFFF0000u; return x.f;
}
__device__ inline float fast_sig(float x) {
  return __builtin_amdgcn_rcpf(1.f + __expf(-x));
}
__device__ inline float fast_tanh(float x) {
  return 1.f - 2.f * __builtin_amdgcn_rcpf(1.f + __expf(2.f * x));
}

// async global->LDS copy, 16B per lane; LDS dest = base + lane*16 (HW rule)
__device__ inline void async_copy16(const void* g, void* l) {
  __builtin_amdgcn_global_load_lds(
      (const __attribute__((address_space(1))) unsigned int*)g,
      (__attribute__((address_space(3))) unsigned int*)l, 16, 0, 0);
}

// ---------------------------------------------------------------------------
// device bodies
// ---------------------------------------------------------------------------

// pack weight matrix into MFMA B-fragment order (16x16x32 bf16).
__device__ inline void packB_body(const float* __restrict__ W,
                                  unsigned short* __restrict__ out,
                                  int K, int Ncols, int ldw, int trans, int bid) {
  int idx = bid * 256 + threadIdx.x;
  int total = (Ncols / 16) * (K / 32) * 64;
  if (idx >= total) return;
  int lane = idx & 63;
  int frag = idx >> 6;
  int kt = K / 32;
  int k0 = frag % kt;
  int n0 = frag / kt;
  int n = n0 * 16 + (lane & 15);
  int kbase = k0 * 32 + (lane >> 4) * 8;
  us8_t v;
#pragma unroll
  for (int j = 0; j < 8; ++j) {
    int k = kbase + j;
    float f = trans ? W[(size_t)n * ldw + k] : W[(size_t)k * ldw + n];
    v[j] = f2bf(f);
  }
  *(us8_t*)(out + (size_t)idx * 8) = v;
}

// atomic-free CSR fill (slot from pos[]), raw weight, NT store. 512 thr.
__device__ inline void fill_body(const int* __restrict__ src, const int* __restrict__ dst,
                                 const float* __restrict__ ew, const int* __restrict__ rowptr,
                                 const int* __restrict__ pos, int2* __restrict__ csr,
                                 int E, int bid) {
  int e = bid * 512 + threadIdx.x;
  if (e >= E) return;
  int d = dst[e];
  int p = rowptr[d] + pos[e];
  unsigned long long v = (unsigned long long)(unsigned)src[e] |
                         ((unsigned long long)(unsigned)__float_as_int(ew[e]) << 32);
  __builtin_nontemporal_store(v, (unsigned long long*)(csr + p));
}

// deg[n] = 1 + sum raw incoming ew; dinv = rsqrt. 512 thr.
__device__ inline void deg_body(const int* __restrict__ rowptr, const int2* __restrict__ csr,
                                float* __restrict__ dinv, int N, int bid) {
  int n = bid * 512 + threadIdx.x;
  if (n >= N) return;
  int b = rowptr[n], e = rowptr[n + 1];
  float s = 1.0f;
  for (int j = b; j < e; ++j) {
    unsigned long long v = __builtin_nontemporal_load((const unsigned long long*)(csr + j));
    s += __int_as_float((int)(v >> 32));
  }
  dinv[n] = rsqrtf(s);
}

// in-place normalize: w = dinv[src] * ew_raw * dinv[dst]. 512 thr.
__device__ inline void norm_body(const int* __restrict__ rowptr, int2* __restrict__ csr,
                                 const float* __restrict__ dinv, int N, int bid) {
  int n = bid * 512 + threadIdx.x;
  if (n >= N) return;
  int b = rowptr[n], e = rowptr[n + 1];
  float dn = dinv[n];
  for (int j = b; j < e; ++j) {
    unsigned long long v = __builtin_nontemporal_load((const unsigned long long*)(csr + j));
    int s = (int)v;
    float w = dinv[s] * __int_as_float((int)(v >> 32)) * dn;
    unsigned long long nv = (unsigned long long)(unsigned)s |
                            ((unsigned long long)(unsigned)__float_as_int(w) << 32);
    __builtin_nontemporal_store(nv, (unsigned long long*)(csr + j));
  }
}

// MFMA GEMM body, 8 waves x 16 rows = 128 rows/block; 32KB smem
__device__ inline void gemm_body8(const unsigned short* __restrict__ A,
                                  const unsigned short* __restrict__ Bp,
                                  const float* __restrict__ bias,
                                  unsigned short* __restrict__ C, int M, int bid,
                                  bool relu, bool hasbias, unsigned char* smem) {
  int wave = threadIdx.x >> 6, lane = threadIdx.x & 63;
  int row0 = (bid * 8 + wave) * 16;
  int m = lane & 15, q = lane >> 4;

#pragma unroll
  for (int i = 0; i < 4; ++i) {
    int f = wave * 4 + i;
    async_copy16((const unsigned char*)Bp + (size_t)f * 1024 + lane * 16,
                 smem + f * 1024);
  }
  __syncthreads();
  if (row0 >= M) return;

  int arow = row0 + m; if (arow >= M) arow = M - 1;
  bf8_t a[4];
#pragma unroll
  for (int k0 = 0; k0 < 4; ++k0)
    a[k0] = *(const bf8_t*)(A + (size_t)arow * 128 + k0 * 32 + q * 8);

#pragma unroll
  for (int n0 = 0; n0 < 8; ++n0) {
    f4_t acc = {};
#pragma unroll
    for (int k0 = 0; k0 < 4; ++k0) {
      bf8_t b = *(const bf8_t*)(smem + (n0 * 4 + k0) * 1024 + lane * 16);
      acc = __builtin_amdgcn_mfma_f32_16x16x32_bf16(a[k0], b, acc, 0, 0, 0);
    }
    int col = n0 * 16 + m;
    float bs = hasbias ? bias[col] : 0.f;
#pragma unroll
    for (int r = 0; r < 4; ++r) {
      int grow = row0 + q * 4 + r;
      if (grow < M) {
        float v = acc[r] + bs;
        if (relu) v = fmaxf(v, 0.f);
        C[(size_t)grow * 128 + col] = f2bf(v);
      }
    }
  }
}

// GRU B-staging, 8 waves: wave stages 3 of 24 frags (frag f: s=f>>2, k0=f&3)
__device__ inline void gru_stage8(const unsigned short* __restrict__ Bi,
                                  const unsigned short* __restrict__ Bh,
                                  unsigned char* smem, int wave, int lane, int g) {
#pragma unroll
  for (int i = 0; i < 3; ++i) {
    int f = wave * 3 + i;
    int s = f >> 2, k0 = f & 3;
    int cc = g + 8 * (s >= 3 ? s - 3 : s);
    const unsigned short* src = (s < 3) ? Bi : Bh;
    async_copy16((const unsigned char*)src + ((size_t)(cc * 4 + k0)) * 1024 + lane * 16,
                 smem + f * 1024);
  }
}

// GRU core: caller prepared ax[4] and issued gru_stage8(...,0).
// ALL 512 threads must enter (barriers inside). In-place h safe (each wave
// touches only its own 16 rows; hprev lookahead reads precede col writes).
// Fully unrolled group loop -> all array indices static (no scratch).
__device__ inline void gru_core(const bf8_t* ax, const float* h_in, float* h_out,
                                const unsigned short* __restrict__ Bi,
                                const unsigned short* __restrict__ Bh,
                                const float* __restrict__ bih, const float* __restrict__ bhh,
                                int M, int row0, int wave, int lane, unsigned char* smem) {
  int m = lane & 15, q = lane >> 4;
  int arow = row0 + m; if (arow >= M) arow = M - 1;

  bf8_t ah[4];
#pragma unroll
  for (int k0 = 0; k0 < 4; ++k0) {
    const float* hp = h_in + (size_t)arow * 128 + k0 * 32 + q * 8;
    float4 h0 = *(const float4*)hp;
    float4 h1 = *(const float4*)(hp + 4);
    bf8_t t;
    t[0] = (short)f2bf(h0.x); t[1] = (short)f2bf(h0.y);
    t[2] = (short)f2bf(h0.z); t[3] = (short)f2bf(h0.w);
    t[4] = (short)f2bf(h1.x); t[5] = (short)f2bf(h1.y);
    t[6] = (short)f2bf(h1.z); t[7] = (short)f2bf(h1.w);
    ah[k0] = t;
  }

  // per-thread epilogue rows (clamped for loads; stores guarded by grow<M)
  int erow[4];
#pragma unroll
  for (int r = 0; r < 4; ++r) {
    int gr = row0 + q * 4 + r;
    erow[r] = (gr < M) ? gr : (M - 1);
  }

  // hprev lookahead: group 0 loaded upfront, group g+1 issued during group g
  float hp_cur[4], hp_nxt[4];
#pragma unroll
  for (int r = 0; r < 4; ++r)
    hp_cur[r] = h_in[(size_t)erow[r] * 128 + m];

#pragma unroll
  for (int g = 0; g < 8; ++g) {
    __syncthreads();   // staging of g complete (vmcnt drained by barrier)
    f4_t air = {}, aiz = {}, ain = {}, ahr = {}, ahz = {}, ahn = {};
#pragma unroll
    for (int k0 = 0; k0 < 4; ++k0) {
      bf8_t br = *(const bf8_t*)(smem + (0 * 4 + k0) * 1024 + lane * 16);
      bf8_t bz = *(const bf8_t*)(smem + (1 * 4 + k0) * 1024 + lane * 16);
      bf8_t bn = *(const bf8_t*)(smem + (2 * 4 + k0) * 1024 + lane * 16);
      bf8_t cr = *(const bf8_t*)(smem + (3 * 4 + k0) * 1024 + lane * 16);
      bf8_t cz = *(const bf8_t*)(smem + (4 * 4 + k0) * 1024 + lane * 16);
      bf8_t cn = *(const bf8_t*)(smem + (5 * 4 + k0) * 1024 + lane * 16);
      air = __builtin_amdgcn_mfma_f32_16x16x32_bf16(ax[k0], br, air, 0, 0, 0);
      aiz = __builtin_amdgcn_mfma_f32_16x16x32_bf16(ax[k0], bz, aiz, 0, 0, 0);
      ain = __builtin_amdgcn_mfma_f32_16x16x32_bf16(ax[k0], bn, ain, 0, 0, 0);
      ahr = __builtin_amdgcn_mfma_f32_16x16x32_bf16(ah[k0], cr, ahr, 0, 0, 0);
      ahz = __builtin_amdgcn_mfma_f32_16x16x32_bf16(ah[k0], cz, ahz, 0, 0, 0);
      ahn = __builtin_amdgcn_mfma_f32_16x16x32_bf16(ah[k0], cn, ahn, 0, 0, 0);
    }
    if (g < 7) {                         // issue next group's hprev loads now
#pragma unroll
      for (int r = 0; r < 4; ++r)
        hp_nxt[r] = h_in[(size_t)erow[r] * 128 + (g + 1) * 16 + m];
    }
    __syncthreads();   // all waves done reading LDS for g
    if (g < 7) gru_stage8(Bi, Bh, smem, wave, lane, g + 1);

    int col = g * 16 + m;
    float bir_ = bih[col], biz_ = bih[col + 128], bin_ = bih[col + 256];
    float bhr_ = bhh[col], bhz_ = bhh[col + 128], bhn_ = bhh[col + 256];
#pragma unroll
    for (int r = 0; r < 4; ++r) {
      int grow = row0 + q * 4 + r;
      if (grow < M) {
        float rr = fast_sig(air[r] + bir_ + ahr[r] + bhr_);
        float zz = fast_sig(aiz[r] + biz_ + ahz[r] + bhz_);
        float nn = fast_tanh(ain[r] + bin_ + rr * (ahn[r] + bhn_));
        h_out[(size_t)grow * 128 + col] = (1.f - zz) * nn + zz * hp_cur[r];
      }
    }
#pragma unroll
    for (int r = 0; r < 4; ++r) hp_cur[r] = hp_nxt[r];
  }
}

// full GRU body for one 8-wave block (reads ax from global xh)
__device__ inline void gru_body8(const unsigned short* __restrict__ xh,
                                 const float* h_in, float* h_out,
                                 const unsigned short* __restrict__ Bi,
                                 const unsigned short* __restrict__ Bh,
                                 const float* __restrict__ bih, const float* __restrict__ bhh,
                                 int M, int bid, unsigned char* smem) {
  int wave = threadIdx.x >> 6, lane = threadIdx.x & 63;
  int row0 = (bid * 8 + wave) * 16;
  gru_stage8(Bi, Bh, smem, wave, lane, 0);
  int m = lane & 15, q = lane >> 4;
  int arow = row0 + m; if (arow >= M) arow = M - 1;
  bf8_t ax[4];
#pragma unroll
  for (int k0 = 0; k0 < 4; ++k0)
    ax[k0] = *(const bf8_t*)(xh + (size_t)arow * 128 + k0 * 32 + q * 8);
  gru_core(ax, h_in, h_out, Bi, Bh, bih, bhh, M, row0, wave, lane, smem);
}

// CSR gather body: 1 node per wave (nodeBase = first node of this block)
__device__ inline void gather_body(
    const int* __restrict__ rowptr, const int2* __restrict__ csr,
    const unsigned* __restrict__ xw, const float* __restrict__ dinv,
    const float* __restrict__ bias, unsigned* __restrict__ out,
    int N, int nodeBase) {
  int wave = threadIdx.x >> 6;
  int lane = threadIdx.x & 63;
  int node = __builtin_amdgcn_readfirstlane(nodeBase + wave);
  if (node >= N) return;
  int beg = __builtin_amdgcn_readfirstlane(rowptr[node]);
  int end = __builtin_amdgcn_readfirstlane(rowptr[node + 1]);

  float accl = 0.f, acch = 0.f;
  int k = beg;
  for (; k + 4 <= end; k += 4) {
    unsigned long long r0 = __builtin_nontemporal_load((const unsigned long long*)(csr + k));
    unsigned long long r1 = __builtin_nontemporal_load((const unsigned long long*)(csr + k + 1));
    unsigned long long r2 = __builtin_nontemporal_load((const unsigned long long*)(csr + k + 2));
    unsigned long long r3 = __builtin_nontemporal_load((const unsigned long long*)(csr + k + 3));
    unsigned v0 = xw[((size_t)(unsigned)r0 << 6) + lane];
    unsigned v1 = xw[((size_t)(unsigned)r1 << 6) + lane];
    unsigned v2 = xw[((size_t)(unsigned)r2 << 6) + lane];
    unsigned v3 = xw[((size_t)(unsigned)r3 << 6) + lane];
    float w0 = __int_as_float((int)(r0 >> 32)), w1 = __int_as_float((int)(r1 >> 32));
    float w2 = __int_as_float((int)(r2 >> 32)), w3 = __int_as_float((int)(r3 >> 32));
    accl += bflo(v0) * w0; acch += bfhi(v0) * w0;
    accl += bflo(v1) * w1; acch += bfhi(v1) * w1;
    accl += bflo(v2) * w2; acch += bfhi(v2) * w2;
    accl += bflo(v3) * w3; acch += bfhi(v3) * w3;
  }
  for (; k < end; ++k) {
    unsigned long long r = __builtin_nontemporal_load((const unsigned long long*)(csr + k));
    unsigned v = xw[((size_t)(unsigned)r << 6) + lane];
    float w = __int_as_float((int)(r >> 32));
    accl += bflo(v) * w; acch += bfhi(v) * w;
  }

  float di = dinv[node];
  float sn = di * di;
  unsigned vs = xw[((size_t)node << 6) + lane];
  float2 b = *(const float2*)(bias + lane * 2);
  float rl = fmaxf(accl + bflo(vs) * sn + b.x, 0.f);
  float rh = fmaxf(acch + bfhi(vs) * sn + b.y, 0.f);
  unsigned o = (unsigned)f2bf(rl) | ((unsigned)f2bf(rh) << 16);
  out[((size_t)node << 6) + lane] = o;
}

// ---------------------------------------------------------------------------
// kernels
// ---------------------------------------------------------------------------

// prep: all 6 weight packs + zero cnt, one launch (256 thr)
__global__ __launch_bounds__(256) void k_prep(
    const float* __restrict__ linW, const float* __restrict__ convW,
    const float* __restrict__ Wih, const float* __restrict__ Whh,
    unsigned short* __restrict__ linWp, unsigned short* __restrict__ convWp,
    unsigned short* __restrict__ Bi, unsigned short* __restrict__ Bh,
    int* __restrict__ cnt, int N) {
  int b = blockIdx.x;
  if (b < 8)  { packB_body(linW, linWp, 128, 128, 128, 0, b); return; }
  if (b < 32) { int l = (b - 8) >> 3;
                packB_body(convW + (size_t)l * 16384, convWp + (size_t)l * 16384,
                           128, 128, 128, 0, (b - 8) & 7); return; }
  if (b < 56) { packB_body(Wih, Bi, 128, 384, 128, 1, b - 32); return; }
  if (b < 80) { packB_body(Whh, Bh, 128, 384, 128, 1, b - 56); return; }
  int i = (b - 80) * 256 + threadIdx.x;
  if (i < N) cnt[i] = 0;
}

// fused: atomic histogram+pos (blocks [0,nCnt)) || f2bf (rest)  (256 thr)
__global__ __launch_bounds__(256) void k_count_f2bf(
    const int* __restrict__ dst, int* __restrict__ cnt, int* __restrict__ pos, int E,
    const float* __restrict__ xin, unsigned short* __restrict__ xout, size_t n8,
    int nCnt) {
  if ((int)blockIdx.x < nCnt) {
    int e = blockIdx.x * 256 + threadIdx.x;
    if (e < E) pos[e] = atomicAdd(&cnt[dst[e]], 1);
    return;
  }
  size_t i = (size_t)(blockIdx.x - nCnt) * 256 + threadIdx.x;
  if (i >= n8) return;
  const float4* p = (const float4*)(xin + i * 8);
  float4 a = p[0], b = p[1];
  us8_t v;
  v[0] = f2bf(a.x); v[1] = f2bf(a.y); v[2] = f2bf(a.z); v[3] = f2bf(a.w);
  v[4] = f2bf(b.x); v[5] = f2bf(b.y); v[6] = f2bf(b.z); v[7] = f2bf(b.w);
  *(us8_t*)(xout + i * 8) = v;
}

// hierarchical scan for rowptr
__global__ __launch_bounds__(256) void k_scan_block(
    const int* __restrict__ cnt, int* __restrict__ partial,
    int* __restrict__ bsum, int n) {
  __shared__ int s[256];
  int tid = threadIdx.x;
  int i = blockIdx.x * 256 + tid;
  s[tid] = (i < n) ? cnt[i] : 0;
  __syncthreads();
#pragma unroll
  for (int d = 1; d < 256; d <<= 1) {
    int t = (tid >= d) ? s[tid - d] : 0;
    __syncthreads();
    s[tid] += t;
    __syncthreads();
  }
  if (i < n) partial[i] = s[tid];
  if (tid == 255) bsum[blockIdx.x] = s[255];
}

__global__ __launch_bounds__(512) void k_scan_sums(int* __restrict__ bsum, int nb) {
  __shared__ int s[512];
  int tid = threadIdx.x;
  s[tid] = (tid < nb) ? bsum[tid] : 0;
  __syncthreads();
#pragma unroll
  for (int d = 1; d < 512; d <<= 1) {
    int t = (tid >= d) ? s[tid - d] : 0;
    __syncthreads();
    s[tid] += t;
    __syncthreads();
  }
  if (tid < nb) bsum[tid] = s[tid];
}

__global__ __launch_bounds__(256) void k_scan_add(
    const int* __restrict__ partial, const int* __restrict__ bsum,
    int* __restrict__ rowptr, int n) {
  int i = blockIdx.x * 256 + threadIdx.x;
  if (i == 0) rowptr[0] = 0;
  if (i < n) {
    int v = partial[i] + (blockIdx.x > 0 ? bsum[blockIdx.x - 1] : 0);
    rowptr[i + 1] = v;
  }
}

// fused: csr_fill (blocks [0,nFill)) || lin GEMM relu+bias (rest)  (512 thr)
__global__ __launch_bounds__(512, 4) void k_fill_lin(
    const int* __restrict__ src, const int* __restrict__ dstI,
    const float* __restrict__ ew, const int* __restrict__ rowptr,
    const int* __restrict__ pos, int2* __restrict__ csr, int E,
    const unsigned short* __restrict__ A, const unsigned short* __restrict__ Bp,
    const float* __restrict__ bias, unsigned short* __restrict__ C, int M,
    int nFill) {
  __shared__ unsigned char smem[32 * 1024];
  if ((int)blockIdx.x < nFill) {
    fill_body(src, dstI, ew, rowptr, pos, csr, E, blockIdx.x);
    return;
  }
  gemm_body8(A, Bp, bias, C, M, blockIdx.x - nFill, true, true, smem);
}

// fused: deg/dinv (blocks [0,nDeg)) || conv0 GEMM (rest)  (512 thr)
__global__ __launch_bounds__(512, 4) void k_deg_conv(
    const int* __restrict__ rowptr, const int2* __restrict__ csr,
    float* __restrict__ dinv, int N,
    const unsigned short* __restrict__ A, const unsigned short* __restrict__ Bp,
    unsigned short* __restrict__ C, int M, int nDeg) {
  __shared__ unsigned char smem[32 * 1024];
  if ((int)blockIdx.x < nDeg) {
    deg_body(rowptr, csr, dinv, N, blockIdx.x);
    return;
  }
  gemm_body8(A, Bp, nullptr, C, M, blockIdx.x - nDeg, false, false, smem);
}

// standalone normalize (512 thr)
__global__ __launch_bounds__(512) void k_norm(
    const int* __restrict__ rowptr, int2* __restrict__ csr,
    const float* __restrict__ dinv, int N) {
  norm_body(rowptr, csr, dinv, N, blockIdx.x);
}

// fused: GRU (blocks [0,nGru)) || CSR gather (rest, 8 nodes/block).
// GRU reads xh_gru (prev layer), gather writes xh_out (other buffer).
__global__ __launch_bounds__(512, 4) void k_gather_gru(
    const int* __restrict__ rowptr, const int2* __restrict__ csr,
    const unsigned* __restrict__ xw, const float* __restrict__ dinv,
    const float* __restrict__ bias, unsigned* __restrict__ xh_out, int N,
    const unsigned short* __restrict__ xh_gru, const float* h_in, float* h_out,
    const unsigned short* __restrict__ Bi, const unsigned short* __restrict__ Bh,
    const float* __restrict__ bih, const float* __restrict__ bhh, int nGru) {
  __shared__ unsigned char smem[24 * 1024];
  if ((int)blockIdx.x < nGru) {
    gru_body8(xh_gru, h_in, h_out, Bi, Bh, bih, bhh, N, blockIdx.x, smem);
    return;
  }
  gather_body(rowptr, csr, xw, dinv, bias, xh_out, N, (blockIdx.x - nGru) * 8);
}

// standalone conv GEMM (512 thr)
__global__ __launch_bounds__(512, 4) void k_conv(
    const unsigned short* __restrict__ A, const unsigned short* __restrict__ Bp,
    unsigned short* __restrict__ C, int M) {
  __shared__ unsigned char smem[32 * 1024];
  gemm_body8(A, Bp, nullptr, C, M, blockIdx.x, false, false, smem);
}

// standalone GRU (final)  (512 thr)
__global__ __launch_bounds__(512, 4) void k_gru(
    const unsigned short* __restrict__ xh, const float* h_in, float* h_out,
    const unsigned short* __restrict__ Bi, const unsigned short* __restrict__ Bh,
    const float* __restrict__ bih, const float* __restrict__ bhh, int M) {
  __shared__ unsigned char smem[24 * 1024];
  gru_body8(xh, h_in, h_out, Bi, Bh, bih, bhh, M, blockIdx.x, smem);
}

// ---------------------------------------------------------------------------
// fp32 GEMM (final fc layer)
// ---------------------------------------------------------------------------

template<bool RELU, bool BIAS>
__global__ __launch_bounds__(256) void k_gemm128(
    const float* __restrict__ A, const float* __restrict__ B,
    const float* __restrict__ bias, float* __restrict__ C, int M, int Nc) {
  __shared__ float As[64][36];
  __shared__ float Bs[32][64];
  int tid = threadIdx.x;
  int tx = tid & 15, ty = tid >> 4;
  int row0 = blockIdx.y * 64, col0 = blockIdx.x * 64;
  float acc[4][4] = {};

  for (int k0 = 0; k0 < 128; k0 += 32) {
#pragma unroll
    for (int i = 0; i < 2; ++i) {
      int f = tid + i * 256;
      int r = f >> 3, c4 = f & 7;
      int gr = row0 + r;
      float4 v = make_float4(0.f, 0.f, 0.f, 0.f);
      if (gr < M) v = *(const float4*)(A + (size_t)gr * 128 + k0 + c4 * 4);
      *(float4*)(&As[r][c4 * 4]) = v;
    }
#pragma unroll
    for (int i = 0; i < 2; ++i) {
      int f = tid + i * 256;
      int r = f >> 4, c4 = f & 15;
      int gc = col0 + c4 * 4;
      float4 v = make_float4(0.f, 0.f, 0.f, 0.f);
      if (gc + 3 < Nc) v = *(const float4*)(B + (size_t)(k0 + r) * Nc + gc);
      *(float4*)(&Bs[r][c4 * 4]) = v;
    }
    __syncthreads();
#pragma unroll
    for (int kk = 0; kk < 32; ++kk) {
      float4 b = *(float4*)(&Bs[kk][tx * 4]);
      float a0 = As[ty * 4 + 0][kk];
      float a1 = As[ty * 4 + 1][kk];
      float a2 = As[ty * 4 + 2][kk];
      float a3 = As[ty * 4 + 3][kk];
      acc[0][0] += a0 * b.x; acc[0][1] += a0 * b.y; acc[0][2] += a0 * b.z; acc[0][3] += a0 * b.w;
      acc[1][0] += a1 * b.x; acc[1][1] += a1 * b.y; acc[1][2] += a1 * b.z; acc[1][3] += a1 * b.w;
      acc[2][0] += a2 * b.x; acc[2][1] += a2 * b.y; acc[2][2] += a2 * b.z; acc[2][3] += a2 * b.w;
      acc[3][0] += a3 * b.x; acc[3][1] += a3 * b.y; acc[3][2] += a3 * b.z; acc[3][3] += a3 * b.w;
    }
    __syncthreads();
  }

#pragma unroll
  for (int i = 0; i < 4; ++i) {
    int gr = row0 + ty * 4 + i;
    if (gr >= M) continue;
#pragma unroll
    for (int j = 0; j < 4; ++j) {
      int gc = col0 + tx * 4 + j;
      if (gc >= Nc) continue;
      float v = acc[i][j];
      if (BIAS) v += bias[gc];
      if (RELU) v = fmaxf(v, 0.f);
      C[(size_t)gr * Nc + gc] = v;
    }
  }
}

// ---------------------------------------------------------------------------

extern "C" void kernel_launch(void* const* d_in, const int* in_sizes, int n_in,
                              void* d_out, int out_size, void* d_ws, size_t ws_size,
                              hipStream_t stream) {
  const float* x    = (const float*)d_in[0];
  const int*   ei   = (const int*)d_in[1];
  const float* ew   = (const float*)d_in[2];
  const float* h0   = (const float*)d_in[3];
  const float* linW = (const float*)d_in[4];
  const float* linB = (const float*)d_in[5];
  const float* convW= (const float*)d_in[6];
  const float* convB= (const float*)d_in[7];
  const float* Wih  = (const float*)d_in[8];
  const float* Whh  = (const float*)d_in[9];
  const float* bih  = (const float*)d_in[10];
  const float* bhh  = (const float*)d_in[11];
  const float* fcW  = (const float*)d_in[12];
  const float* fcB  = (const float*)d_in[13];

  int N = in_sizes[0] / 128;
  int E = in_sizes[1] / 2;
  const int* srcI = ei;
  const int* dstI = ei + E;
  int nb = (N + 255) / 256;

  // ---- workspace layout ----
  float* ws = (float*)d_ws;
  size_t off = 0;
  float* dinv = ws + off; off += (size_t)N;
  if (off & 1) off++;                       // 8B-align what follows
  float* h    = ws + off; off += (size_t)N * 128;
  int* iws = (int*)(ws + off);              // 8B-aligned
  size_t ioff = 0;
  int2* csr    = (int2*)iws; ioff += (size_t)2 * E;
  int* cnt     = iws + ioff; ioff += (size_t)N;
  int* partial = iws + ioff; ioff += (size_t)N;
  int* bsum    = iws + ioff; ioff += 512;
  int* rowptr  = iws + ioff; ioff += (size_t)N + 1;
  ioff = (ioff + 3) & ~(size_t)3;           // 16B-align ushort area
  unsigned short* usws = (unsigned short*)(iws + ioff);
  size_t uoff = 0;
  unsigned short* x_bf   = usws + uoff; uoff += (size_t)N * 128;
  unsigned short* xh_bf  = usws + uoff; uoff += (size_t)N * 128;
  unsigned short* xw_bf  = usws + uoff; uoff += (size_t)N * 128;
  unsigned short* linWp  = usws + uoff; uoff += 128 * 128;
  unsigned short* convWp = usws + uoff; uoff += 3 * 128 * 128;
  unsigned short* Bi     = usws + uoff; uoff += 384 * 128;
  unsigned short* Bh     = usws + uoff; uoff += 384 * 128;

  // Aliases with disjoint lifetimes:
  //   pos[E] aliases xw_bf (pos dies at k_fill_lin; xw first written at k_deg_conv)
  //   xhB aliases x_bf (x_bf last read by lin GEMM; xhB first written by gather0)
  int* pos = (int*)xw_bf;
  unsigned short* xhA = xh_bf;
  unsigned short* xhB = x_bf;

  int gw8   = (N + 127) / 128;      // 8 waves x 16 rows per block
  int nCnt  = (E + 255) / 256;
  int nF2   = (int)(((size_t)N * 16 + 255) / 256);
  int n512  = (N + 511) / 512;
  int e512  = (E + 511) / 512;
  int nGat8 = (N + 7) / 8;          // 1 node/wave, 8 waves/block

  // 1) packs + zero cnt
  k_prep<<<80 + nb, 256, 0, stream>>>(linW, convW, Wih, Whh,
                                      linWp, convWp, Bi, Bh, cnt, N);
  // 2) count+pos || x->bf16
  k_count_f2bf<<<nCnt + nF2, 256, 0, stream>>>(dstI, cnt, pos, E,
                                               x, x_bf, (size_t)N * 16, nCnt);
  // 3-5) rowptr scan
  k_scan_block<<<nb, 256, 0, stream>>>(cnt, partial, bsum, N);
  k_scan_sums<<<1, 512, 0, stream>>>(bsum, nb);
  k_scan_add<<<nb, 256, 0, stream>>>(partial, bsum, rowptr, N);
  // 6) csr fill || xhA = relu(x@linW + linB)
  k_fill_lin<<<e512 + gw8, 512, 0, stream>>>(srcI, dstI, ew, rowptr, pos, csr, E,
                                             x_bf, linWp, linB, xhA, N, e512);
  // 7) deg/dinv || conv0 (xhA -> xw)
  k_deg_conv<<<n512 + gw8, 512, 0, stream>>>(rowptr, csr, dinv, N,
                                             xhA, convWp, xw_bf, N, n512);
  // 8) normalize csr weights
  k_norm<<<n512, 512, 0, stream>>>(rowptr, csr, dinv, N);
  // 9) GRU#1 (xhA, h0 -> h) || gather0 (xw -> xhB)
  k_gather_gru<<<gw8 + nGat8, 512, 0, stream>>>(
      rowptr, csr, (const unsigned*)xw_bf, dinv, convB, (unsigned*)xhB, N,
      xhA, h0, h, Bi, Bh, bih, bhh, gw8);
  // 10) conv1 (xhB -> xw)
  k_conv<<<gw8, 512, 0, stream>>>(xhB, convWp + (size_t)1 * 128 * 128, xw_bf, N);
  // 11) GRU#2 (xhB, h -> h) || gather1 (xw -> xhA)
  k_gather_gru<<<gw8 + nGat8, 512, 0, stream>>>(
      rowptr, csr, (const unsigned*)xw_bf, dinv, convB + 128, (unsigned*)xhA, N,
      xhB, h, h, Bi, Bh, bih, bhh, gw8);
  // 12) conv2 (xhA -> xw)
  k_conv<<<gw8, 512, 0, stream>>>(xhA, convWp + (size_t)2 * 128 * 128, xw_bf, N);
  // 13) GRU#3 (xhA, h -> h) || gather2 (xw -> xhB)
  k_gather_gru<<<gw8 + nGat8, 512, 0, stream>>>(
      rowptr, csr, (const unsigned*)xw_bf, dinv, convB + 256, (unsigned*)xhB, N,
      xhA, h, h, Bi, Bh, bih, bhh, gw8);
  // 14) GRU#4 (xhB, h -> h)
  k_gru<<<gw8, 512, 0, stream>>>(xhB, h, h, Bi, Bh, bih, bhh, N);
  // 15) out = h @ fcW + fcB (fp32)
  dim3 g40(1, (N + 63) / 64);
  k_gemm128<false, true><<<g40, 256, 0, stream>>>(h, fcW, fcB, (float*)d_out, N, 40);
}

// Round 6
// 982.344 us; speedup vs baseline: 1.2019x; 1.2019x over previous
//
#include <hip/hip_runtime.h>
#include <hip/hip_bf16.h>
#include <math.h>

typedef __attribute__((ext_vector_type(8))) short bf8_t;   // 8 x bf16 (4 VGPRs)
typedef __attribute__((ext_vector_type(4))) float f4_t;    // MFMA accumulator
typedef __attribute__((ext_vector_type(8))) unsigned short us8_t;

__device__ inline unsigned short f2bf(float f) {
  union { float f; unsigned u; } x; x.f = f;
  unsigned r = x.u + 0x7FFF + ((x.u >> 16) & 1);   // RNE
  return (unsigned short)(r >> 16);
}
__device__ inline float bflo(unsigned v) {
  union { unsigned u; float f; } x; x.u = v << 16; return x.f;
}
__device__ inline float bfhi(unsigned v) {
  union { unsigned u; float f; } x; x.u = v & 0xFFFF0000u; return x.f;
}
__device__ inline float fast_sig(float x) {
  return __builtin_amdgcn_rcpf(1.f + __expf(-x));
}
__device__ inline float fast_tanh(float x) {
  return 1.f - 2.f * __builtin_amdgcn_rcpf(1.f + __expf(2.f * x));
}

// async global->LDS copy, 16B per lane; LDS dest = base + lane*16 (HW rule)
__device__ inline void async_copy16(const void* g, void* l) {
  __builtin_amdgcn_global_load_lds(
      (const __attribute__((address_space(1))) unsigned int*)g,
      (__attribute__((address_space(3))) unsigned int*)l, 16, 0, 0);
}

// ---------------------------------------------------------------------------
// device bodies
// ---------------------------------------------------------------------------

// pack weight matrix into MFMA B-fragment order (16x16x32 bf16).
__device__ inline void packB_body(const float* __restrict__ W,
                                  unsigned short* __restrict__ out,
                                  int K, int Ncols, int ldw, int trans, int bid) {
  int idx = bid * 256 + threadIdx.x;
  int total = (Ncols / 16) * (K / 32) * 64;
  if (idx >= total) return;
  int lane = idx & 63;
  int frag = idx >> 6;
  int kt = K / 32;
  int k0 = frag % kt;
  int n0 = frag / kt;
  int n = n0 * 16 + (lane & 15);
  int kbase = k0 * 32 + (lane >> 4) * 8;
  us8_t v;
#pragma unroll
  for (int j = 0; j < 8; ++j) {
    int k = kbase + j;
    float f = trans ? W[(size_t)n * ldw + k] : W[(size_t)k * ldw + n];
    v[j] = f2bf(f);
  }
  *(us8_t*)(out + (size_t)idx * 8) = v;
}

// MFMA GEMM body, 8 waves x 16 rows = 128 rows/block; 32KB smem
__device__ inline void gemm_body8(const unsigned short* __restrict__ A,
                                  const unsigned short* __restrict__ Bp,
                                  const float* __restrict__ bias,
                                  unsigned short* __restrict__ C, int M, int bid,
                                  bool relu, bool hasbias, unsigned char* smem) {
  int wave = threadIdx.x >> 6, lane = threadIdx.x & 63;
  int row0 = (bid * 8 + wave) * 16;
  int m = lane & 15, q = lane >> 4;

#pragma unroll
  for (int i = 0; i < 4; ++i) {
    int f = wave * 4 + i;
    async_copy16((const unsigned char*)Bp + (size_t)f * 1024 + lane * 16,
                 smem + f * 1024);
  }
  __syncthreads();
  if (row0 >= M) return;

  int arow = row0 + m; if (arow >= M) arow = M - 1;
  bf8_t a[4];
#pragma unroll
  for (int k0 = 0; k0 < 4; ++k0)
    a[k0] = *(const bf8_t*)(A + (size_t)arow * 128 + k0 * 32 + q * 8);

#pragma unroll
  for (int n0 = 0; n0 < 8; ++n0) {
    f4_t acc = {};
#pragma unroll
    for (int k0 = 0; k0 < 4; ++k0) {
      bf8_t b = *(const bf8_t*)(smem + (n0 * 4 + k0) * 1024 + lane * 16);
      acc = __builtin_amdgcn_mfma_f32_16x16x32_bf16(a[k0], b, acc, 0, 0, 0);
    }
    int col = n0 * 16 + m;
    float bs = hasbias ? bias[col] : 0.f;
#pragma unroll
    for (int r = 0; r < 4; ++r) {
      int grow = row0 + q * 4 + r;
      if (grow < M) {
        float v = acc[r] + bs;
        if (relu) v = fmaxf(v, 0.f);
        C[(size_t)grow * 128 + col] = f2bf(v);
      }
    }
  }
}

// GRU B-staging, 8 waves: wave stages 3 of 24 frags (frag f: s=f>>2, k0=f&3)
__device__ inline void gru_stage8(const unsigned short* __restrict__ Bi,
                                  const unsigned short* __restrict__ Bh,
                                  unsigned char* smem, int wave, int lane, int g) {
#pragma unroll
  for (int i = 0; i < 3; ++i) {
    int f = wave * 3 + i;
    int s = f >> 2, k0 = f & 3;
    int cc = g + 8 * (s >= 3 ? s - 3 : s);
    const unsigned short* src = (s < 3) ? Bi : Bh;
    async_copy16((const unsigned char*)src + ((size_t)(cc * 4 + k0)) * 1024 + lane * 16,
                 smem + f * 1024);
  }
}

// GRU core. ALL 512 threads enter (barriers inside). In-place h safe (each
// wave touches only its own 16 rows; lookahead reads cols of g+1 before
// writing cols of g). Fully unrolled -> static indices, no scratch.
__device__ inline void gru_core(const bf8_t* ax, const float* h_in, float* h_out,
                                const unsigned short* __restrict__ Bi,
                                const unsigned short* __restrict__ Bh,
                                const float* __restrict__ bih, const float* __restrict__ bhh,
                                int M, int row0, int wave, int lane, unsigned char* smem) {
  int m = lane & 15, q = lane >> 4;
  int arow = row0 + m; if (arow >= M) arow = M - 1;

  bf8_t ah[4];
#pragma unroll
  for (int k0 = 0; k0 < 4; ++k0) {
    const float* hp = h_in + (size_t)arow * 128 + k0 * 32 + q * 8;
    float4 h0 = *(const float4*)hp;
    float4 h1 = *(const float4*)(hp + 4);
    bf8_t t;
    t[0] = (short)f2bf(h0.x); t[1] = (short)f2bf(h0.y);
    t[2] = (short)f2bf(h0.z); t[3] = (short)f2bf(h0.w);
    t[4] = (short)f2bf(h1.x); t[5] = (short)f2bf(h1.y);
    t[6] = (short)f2bf(h1.z); t[7] = (short)f2bf(h1.w);
    ah[k0] = t;
  }

  // per-thread epilogue rows (clamped for loads; stores guarded by grow<M)
  int erow[4];
#pragma unroll
  for (int r = 0; r < 4; ++r) {
    int gr = row0 + q * 4 + r;
    erow[r] = (gr < M) ? gr : (M - 1);
  }

  // hprev lookahead: group 0 loaded upfront, group g+1 issued during group g
  float hp_cur[4], hp_nxt[4];
#pragma unroll
  for (int r = 0; r < 4; ++r)
    hp_cur[r] = h_in[(size_t)erow[r] * 128 + m];

#pragma unroll
  for (int g = 0; g < 8; ++g) {
    __syncthreads();   // staging of g complete (vmcnt drained by barrier)
    f4_t air = {}, aiz = {}, ain = {}, ahr = {}, ahz = {}, ahn = {};
#pragma unroll
    for (int k0 = 0; k0 < 4; ++k0) {
      bf8_t br = *(const bf8_t*)(smem + (0 * 4 + k0) * 1024 + lane * 16);
      bf8_t bz = *(const bf8_t*)(smem + (1 * 4 + k0) * 1024 + lane * 16);
      bf8_t bn = *(const bf8_t*)(smem + (2 * 4 + k0) * 1024 + lane * 16);
      bf8_t cr = *(const bf8_t*)(smem + (3 * 4 + k0) * 1024 + lane * 16);
      bf8_t cz = *(const bf8_t*)(smem + (4 * 4 + k0) * 1024 + lane * 16);
      bf8_t cn = *(const bf8_t*)(smem + (5 * 4 + k0) * 1024 + lane * 16);
      air = __builtin_amdgcn_mfma_f32_16x16x32_bf16(ax[k0], br, air, 0, 0, 0);
      aiz = __builtin_amdgcn_mfma_f32_16x16x32_bf16(ax[k0], bz, aiz, 0, 0, 0);
      ain = __builtin_amdgcn_mfma_f32_16x16x32_bf16(ax[k0], bn, ain, 0, 0, 0);
      ahr = __builtin_amdgcn_mfma_f32_16x16x32_bf16(ah[k0], cr, ahr, 0, 0, 0);
      ahz = __builtin_amdgcn_mfma_f32_16x16x32_bf16(ah[k0], cz, ahz, 0, 0, 0);
      ahn = __builtin_amdgcn_mfma_f32_16x16x32_bf16(ah[k0], cn, ahn, 0, 0, 0);
    }
    if (g < 7) {                         // issue next group's hprev loads now
#pragma unroll
      for (int r = 0; r < 4; ++r)
        hp_nxt[r] = h_in[(size_t)erow[r] * 128 + (g + 1) * 16 + m];
    }
    __syncthreads();   // all waves done reading LDS for g
    if (g < 7) gru_stage8(Bi, Bh, smem, wave, lane, g + 1);

    int col = g * 16 + m;
    float bir_ = bih[col], biz_ = bih[col + 128], bin_ = bih[col + 256];
    float bhr_ = bhh[col], bhz_ = bhh[col + 128], bhn_ = bhh[col + 256];
#pragma unroll
    for (int r = 0; r < 4; ++r) {
      int grow = row0 + q * 4 + r;
      if (grow < M) {
        float rr = fast_sig(air[r] + bir_ + ahr[r] + bhr_);
        float zz = fast_sig(aiz[r] + biz_ + ahz[r] + bhz_);
        float nn = fast_tanh(ain[r] + bin_ + rr * (ahn[r] + bhn_));
        h_out[(size_t)grow * 128 + col] = (1.f - zz) * nn + zz * hp_cur[r];
      }
    }
#pragma unroll
    for (int r = 0; r < 4; ++r) hp_cur[r] = hp_nxt[r];
  }
}

// ---------------------------------------------------------------------------
// kernels (all standalone; only count||f2bf fused — atomic-pipe + stream,
// no cache coupling. R5 lesson: keep cache-sensitive gather isolated.)
// ---------------------------------------------------------------------------

// prep: all 6 weight packs + zero cnt, one launch (256 thr)
__global__ __launch_bounds__(256) void k_prep(
    const float* __restrict__ linW, const float* __restrict__ convW,
    const float* __restrict__ Wih, const float* __restrict__ Whh,
    unsigned short* __restrict__ linWp, unsigned short* __restrict__ convWp,
    unsigned short* __restrict__ Bi, unsigned short* __restrict__ Bh,
    int* __restrict__ cnt, int N) {
  int b = blockIdx.x;
  if (b < 8)  { packB_body(linW, linWp, 128, 128, 128, 0, b); return; }
  if (b < 32) { int l = (b - 8) >> 3;
                packB_body(convW + (size_t)l * 16384, convWp + (size_t)l * 16384,
                           128, 128, 128, 0, (b - 8) & 7); return; }
  if (b < 56) { packB_body(Wih, Bi, 128, 384, 128, 1, b - 32); return; }
  if (b < 80) { packB_body(Whh, Bh, 128, 384, 128, 1, b - 56); return; }
  int i = (b - 80) * 256 + threadIdx.x;
  if (i < N) cnt[i] = 0;
}

// fused: atomic histogram+pos (blocks [0,nCnt)) || f2bf (rest)  (256 thr)
__global__ __launch_bounds__(256) void k_count_f2bf(
    const int* __restrict__ dst, int* __restrict__ cnt, int* __restrict__ pos, int E,
    const float* __restrict__ xin, unsigned short* __restrict__ xout, size_t n8,
    int nCnt) {
  if ((int)blockIdx.x < nCnt) {
    int e = blockIdx.x * 256 + threadIdx.x;
    if (e < E) pos[e] = atomicAdd(&cnt[dst[e]], 1);
    return;
  }
  size_t i = (size_t)(blockIdx.x - nCnt) * 256 + threadIdx.x;
  if (i >= n8) return;
  const float4* p = (const float4*)(xin + i * 8);
  float4 a = p[0], b = p[1];
  us8_t v;
  v[0] = f2bf(a.x); v[1] = f2bf(a.y); v[2] = f2bf(a.z); v[3] = f2bf(a.w);
  v[4] = f2bf(b.x); v[5] = f2bf(b.y); v[6] = f2bf(b.z); v[7] = f2bf(b.w);
  *(us8_t*)(xout + i * 8) = v;
}

// hierarchical scan for rowptr
__global__ __launch_bounds__(256) void k_scan_block(
    const int* __restrict__ cnt, int* __restrict__ partial,
    int* __restrict__ bsum, int n) {
  __shared__ int s[256];
  int tid = threadIdx.x;
  int i = blockIdx.x * 256 + tid;
  s[tid] = (i < n) ? cnt[i] : 0;
  __syncthreads();
#pragma unroll
  for (int d = 1; d < 256; d <<= 1) {
    int t = (tid >= d) ? s[tid - d] : 0;
    __syncthreads();
    s[tid] += t;
    __syncthreads();
  }
  if (i < n) partial[i] = s[tid];
  if (tid == 255) bsum[blockIdx.x] = s[255];
}

__global__ __launch_bounds__(512) void k_scan_sums(int* __restrict__ bsum, int nb) {
  __shared__ int s[512];
  int tid = threadIdx.x;
  s[tid] = (tid < nb) ? bsum[tid] : 0;
  __syncthreads();
#pragma unroll
  for (int d = 1; d < 512; d <<= 1) {
    int t = (tid >= d) ? s[tid - d] : 0;
    __syncthreads();
    s[tid] += t;
    __syncthreads();
  }
  if (tid < nb) bsum[tid] = s[tid];
}

__global__ __launch_bounds__(256) void k_scan_add(
    const int* __restrict__ partial, const int* __restrict__ bsum,
    int* __restrict__ rowptr, int n) {
  int i = blockIdx.x * 256 + threadIdx.x;
  if (i == 0) rowptr[0] = 0;
  if (i < n) {
    int v = partial[i] + (blockIdx.x > 0 ? bsum[blockIdx.x - 1] : 0);
    rowptr[i + 1] = v;
  }
}

// atomic-free CSR fill (slot from pos[]), raw weight, NT store (512 thr)
__global__ __launch_bounds__(512) void k_fill(
    const int* __restrict__ src, const int* __restrict__ dst,
    const float* __restrict__ ew, const int* __restrict__ rowptr,
    const int* __restrict__ pos, int2* __restrict__ csr, int E) {
  int e = blockIdx.x * 512 + threadIdx.x;
  if (e >= E) return;
  int d = dst[e];
  int p = rowptr[d] + pos[e];
  unsigned long long v = (unsigned long long)(unsigned)src[e] |
                         ((unsigned long long)(unsigned)__float_as_int(ew[e]) << 32);
  __builtin_nontemporal_store(v, (unsigned long long*)(csr + p));
}

// deg[n] = 1 + sum raw incoming ew; dinv = rsqrt (512 thr)
__global__ __launch_bounds__(512) void k_deg(
    const int* __restrict__ rowptr, const int2* __restrict__ csr,
    float* __restrict__ dinv, int N) {
  int n = blockIdx.x * 512 + threadIdx.x;
  if (n >= N) return;
  int b = rowptr[n], e = rowptr[n + 1];
  float s = 1.0f;
  for (int j = b; j < e; ++j) {
    unsigned long long v = __builtin_nontemporal_load((const unsigned long long*)(csr + j));
    s += __int_as_float((int)(v >> 32));
  }
  dinv[n] = rsqrtf(s);
}

// in-place normalize: w = dinv[src] * ew_raw * dinv[dst] (512 thr)
__global__ __launch_bounds__(512) void k_norm(
    const int* __restrict__ rowptr, int2* __restrict__ csr,
    const float* __restrict__ dinv, int N) {
  int n = blockIdx.x * 512 + threadIdx.x;
  if (n >= N) return;
  int b = rowptr[n], e = rowptr[n + 1];
  float dn = dinv[n];
  for (int j = b; j < e; ++j) {
    unsigned long long v = __builtin_nontemporal_load((const unsigned long long*)(csr + j));
    int s = (int)v;
    float w = dinv[s] * __int_as_float((int)(v >> 32)) * dn;
    unsigned long long nv = (unsigned long long)(unsigned)s |
                            ((unsigned long long)(unsigned)__float_as_int(w) << 32);
    __builtin_nontemporal_store(nv, (unsigned long long*)(csr + j));
  }
}

// MFMA GEMM (lin / conv), 512 thr
template<bool RELU, bool BIAS>
__global__ __launch_bounds__(512, 4) void k_gemm(
    const unsigned short* __restrict__ A, const unsigned short* __restrict__ Bp,
    const float* __restrict__ bias, unsigned short* __restrict__ C, int M) {
  __shared__ unsigned char smem[32 * 1024];
  gemm_body8(A, Bp, bias, C, M, blockIdx.x, RELU, BIAS, smem);
}

// standalone GRU (512 thr)
__global__ __launch_bounds__(512, 4) void k_gru(
    const unsigned short* __restrict__ xh, const float* h_in, float* h_out,
    const unsigned short* __restrict__ Bi, const unsigned short* __restrict__ Bh,
    const float* __restrict__ bih, const float* __restrict__ bhh, int M) {
  __shared__ unsigned char smem[24 * 1024];
  int wave = threadIdx.x >> 6, lane = threadIdx.x & 63;
  int row0 = (blockIdx.x * 8 + wave) * 16;
  gru_stage8(Bi, Bh, smem, wave, lane, 0);
  int m = lane & 15, q = lane >> 4;
  int arow = row0 + m; if (arow >= M) arow = M - 1;
  bf8_t ax[4];
#pragma unroll
  for (int k0 = 0; k0 < 4; ++k0)
    ax[k0] = *(const bf8_t*)(xh + (size_t)arow * 128 + k0 * 32 + q * 8);
  gru_core(ax, h_in, h_out, Bi, Bh, bih, bhh, M, row0, wave, lane, smem);
}

// ---------------------------------------------------------------------------
// CSR gather aggregation: 1 node per wave (max TLP), 4 waves/block (256 thr).
// NT loads on the streamed CSR protect L2 for the random xw gathers.
// ---------------------------------------------------------------------------

__global__ __launch_bounds__(256) void k_gather(
    const int* __restrict__ rowptr, const int2* __restrict__ csr,
    const unsigned* __restrict__ xw,   // [N,64] packed bf16x2
    const float* __restrict__ dinv, const float* __restrict__ bias,
    unsigned* __restrict__ out, int N) {
  int wave = threadIdx.x >> 6;
  int lane = threadIdx.x & 63;
  int node = __builtin_amdgcn_readfirstlane(blockIdx.x * 4 + wave);
  if (node >= N) return;
  int beg = __builtin_amdgcn_readfirstlane(rowptr[node]);
  int end = __builtin_amdgcn_readfirstlane(rowptr[node + 1]);

  float accl = 0.f, acch = 0.f;
  int k = beg;
  for (; k + 4 <= end; k += 4) {
    unsigned long long r0 = __builtin_nontemporal_load((const unsigned long long*)(csr + k));
    unsigned long long r1 = __builtin_nontemporal_load((const unsigned long long*)(csr + k + 1));
    unsigned long long r2 = __builtin_nontemporal_load((const unsigned long long*)(csr + k + 2));
    unsigned long long r3 = __builtin_nontemporal_load((const unsigned long long*)(csr + k + 3));
    unsigned v0 = xw[((size_t)(unsigned)r0 << 6) + lane];
    unsigned v1 = xw[((size_t)(unsigned)r1 << 6) + lane];
    unsigned v2 = xw[((size_t)(unsigned)r2 << 6) + lane];
    unsigned v3 = xw[((size_t)(unsigned)r3 << 6) + lane];
    float w0 = __int_as_float((int)(r0 >> 32)), w1 = __int_as_float((int)(r1 >> 32));
    float w2 = __int_as_float((int)(r2 >> 32)), w3 = __int_as_float((int)(r3 >> 32));
    accl += bflo(v0) * w0; acch += bfhi(v0) * w0;
    accl += bflo(v1) * w1; acch += bfhi(v1) * w1;
    accl += bflo(v2) * w2; acch += bfhi(v2) * w2;
    accl += bflo(v3) * w3; acch += bfhi(v3) * w3;
  }
  for (; k < end; ++k) {
    unsigned long long r = __builtin_nontemporal_load((const unsigned long long*)(csr + k));
    unsigned v = xw[((size_t)(unsigned)r << 6) + lane];
    float w = __int_as_float((int)(r >> 32));
    accl += bflo(v) * w; acch += bfhi(v) * w;
  }

  float di = dinv[node];
  float sn = di * di;
  unsigned vs = xw[((size_t)node << 6) + lane];
  float2 b = *(const float2*)(bias + lane * 2);
  float rl = fmaxf(accl + bflo(vs) * sn + b.x, 0.f);
  float rh = fmaxf(acch + bfhi(vs) * sn + b.y, 0.f);
  unsigned o = (unsigned)f2bf(rl) | ((unsigned)f2bf(rh) << 16);
  out[((size_t)node << 6) + lane] = o;
}

// ---------------------------------------------------------------------------
// fp32 GEMM (final fc layer)
// ---------------------------------------------------------------------------

template<bool RELU, bool BIAS>
__global__ __launch_bounds__(256) void k_gemm128(
    const float* __restrict__ A, const float* __restrict__ B,
    const float* __restrict__ bias, float* __restrict__ C, int M, int Nc) {
  __shared__ float As[64][36];
  __shared__ float Bs[32][64];
  int tid = threadIdx.x;
  int tx = tid & 15, ty = tid >> 4;
  int row0 = blockIdx.y * 64, col0 = blockIdx.x * 64;
  float acc[4][4] = {};

  for (int k0 = 0; k0 < 128; k0 += 32) {
#pragma unroll
    for (int i = 0; i < 2; ++i) {
      int f = tid + i * 256;
      int r = f >> 3, c4 = f & 7;
      int gr = row0 + r;
      float4 v = make_float4(0.f, 0.f, 0.f, 0.f);
      if (gr < M) v = *(const float4*)(A + (size_t)gr * 128 + k0 + c4 * 4);
      *(float4*)(&As[r][c4 * 4]) = v;
    }
#pragma unroll
    for (int i = 0; i < 2; ++i) {
      int f = tid + i * 256;
      int r = f >> 4, c4 = f & 15;
      int gc = col0 + c4 * 4;
      float4 v = make_float4(0.f, 0.f, 0.f, 0.f);
      if (gc + 3 < Nc) v = *(const float4*)(B + (size_t)(k0 + r) * Nc + gc);
      *(float4*)(&Bs[r][c4 * 4]) = v;
    }
    __syncthreads();
#pragma unroll
    for (int kk = 0; kk < 32; ++kk) {
      float4 b = *(float4*)(&Bs[kk][tx * 4]);
      float a0 = As[ty * 4 + 0][kk];
      float a1 = As[ty * 4 + 1][kk];
      float a2 = As[ty * 4 + 2][kk];
      float a3 = As[ty * 4 + 3][kk];
      acc[0][0] += a0 * b.x; acc[0][1] += a0 * b.y; acc[0][2] += a0 * b.z; acc[0][3] += a0 * b.w;
      acc[1][0] += a1 * b.x; acc[1][1] += a1 * b.y; acc[1][2] += a1 * b.z; acc[1][3] += a1 * b.w;
      acc[2][0] += a2 * b.x; acc[2][1] += a2 * b.y; acc[2][2] += a2 * b.z; acc[2][3] += a2 * b.w;
      acc[3][0] += a3 * b.x; acc[3][1] += a3 * b.y; acc[3][2] += a3 * b.z; acc[3][3] += a3 * b.w;
    }
    __syncthreads();
  }

#pragma unroll
  for (int i = 0; i < 4; ++i) {
    int gr = row0 + ty * 4 + i;
    if (gr >= M) continue;
#pragma unroll
    for (int j = 0; j < 4; ++j) {
      int gc = col0 + tx * 4 + j;
      if (gc >= Nc) continue;
      float v = acc[i][j];
      if (BIAS) v += bias[gc];
      if (RELU) v = fmaxf(v, 0.f);
      C[(size_t)gr * Nc + gc] = v;
    }
  }
}

// ---------------------------------------------------------------------------

extern "C" void kernel_launch(void* const* d_in, const int* in_sizes, int n_in,
                              void* d_out, int out_size, void* d_ws, size_t ws_size,
                              hipStream_t stream) {
  const float* x    = (const float*)d_in[0];
  const int*   ei   = (const int*)d_in[1];
  const float* ew   = (const float*)d_in[2];
  const float* h0   = (const float*)d_in[3];
  const float* linW = (const float*)d_in[4];
  const float* linB = (const float*)d_in[5];
  const float* convW= (const float*)d_in[6];
  const float* convB= (const float*)d_in[7];
  const float* Wih  = (const float*)d_in[8];
  const float* Whh  = (const float*)d_in[9];
  const float* bih  = (const float*)d_in[10];
  const float* bhh  = (const float*)d_in[11];
  const float* fcW  = (const float*)d_in[12];
  const float* fcB  = (const float*)d_in[13];

  int N = in_sizes[0] / 128;
  int E = in_sizes[1] / 2;
  const int* srcI = ei;
  const int* dstI = ei + E;
  int nb = (N + 255) / 256;

  // ---- workspace layout ----
  float* ws = (float*)d_ws;
  size_t off = 0;
  float* dinv = ws + off; off += (size_t)N;
  if (off & 1) off++;                       // 8B-align what follows
  float* h    = ws + off; off += (size_t)N * 128;
  int* iws = (int*)(ws + off);              // 8B-aligned
  size_t ioff = 0;
  int2* csr    = (int2*)iws; ioff += (size_t)2 * E;
  int* cnt     = iws + ioff; ioff += (size_t)N;
  int* partial = iws + ioff; ioff += (size_t)N;
  int* bsum    = iws + ioff; ioff += 512;
  int* rowptr  = iws + ioff; ioff += (size_t)N + 1;
  ioff = (ioff + 3) & ~(size_t)3;           // 16B-align ushort area
  unsigned short* usws = (unsigned short*)(iws + ioff);
  size_t uoff = 0;
  unsigned short* x_bf   = usws + uoff; uoff += (size_t)N * 128;
  unsigned short* xh_bf  = usws + uoff; uoff += (size_t)N * 128;
  unsigned short* xw_bf  = usws + uoff; uoff += (size_t)N * 128;
  unsigned short* linWp  = usws + uoff; uoff += 128 * 128;
  unsigned short* convWp = usws + uoff; uoff += 3 * 128 * 128;
  unsigned short* Bi     = usws + uoff; uoff += 384 * 128;
  unsigned short* Bh     = usws + uoff; uoff += 384 * 128;

  // pos[E] aliases xw_bf (pos dies at k_fill; xw first written by conv0)
  int* pos = (int*)xw_bf;

  int gw8  = (N + 127) / 128;       // 8 waves x 16 rows per block
  int nCnt = (E + 255) / 256;
  int nF2  = (int)(((size_t)N * 16 + 255) / 256);
  int n512 = (N + 511) / 512;
  int e512 = (E + 511) / 512;
  int ggat = (N + 3) / 4;           // 1 node/wave, 4 waves/block

  // 1) packs + zero cnt
  k_prep<<<80 + nb, 256, 0, stream>>>(linW, convW, Wih, Whh,
                                      linWp, convWp, Bi, Bh, cnt, N);
  // 2) count+pos || x->bf16
  k_count_f2bf<<<nCnt + nF2, 256, 0, stream>>>(dstI, cnt, pos, E,
                                               x, x_bf, (size_t)N * 16, nCnt);
  // 3-5) rowptr scan
  k_scan_block<<<nb, 256, 0, stream>>>(cnt, partial, bsum, N);
  k_scan_sums<<<1, 512, 0, stream>>>(bsum, nb);
  k_scan_add<<<nb, 256, 0, stream>>>(partial, bsum, rowptr, N);
  // 6) csr fill (atomic-free)
  k_fill<<<e512, 512, 0, stream>>>(srcI, dstI, ew, rowptr, pos, csr, E);
  // 7) deg/dinv
  k_deg<<<n512, 512, 0, stream>>>(rowptr, csr, dinv, N);
  // 8) normalize csr weights
  k_norm<<<n512, 512, 0, stream>>>(rowptr, csr, dinv, N);
  // 9) xh = relu(x@linW + linB)
  k_gemm<true, true><<<gw8, 512, 0, stream>>>(x_bf, linWp, linB, xh_bf, N);
  // 10) GRU#1 (h0 -> h)
  k_gru<<<gw8, 512, 0, stream>>>(xh_bf, h0, h, Bi, Bh, bih, bhh, N);
  // 11-19) 3x { conv, gather, GRU }
  for (int l = 0; l < 3; ++l) {
    k_gemm<false, false><<<gw8, 512, 0, stream>>>(
        xh_bf, convWp + (size_t)l * 128 * 128, nullptr, xw_bf, N);
    k_gather<<<ggat, 256, 0, stream>>>(
        rowptr, csr, (const unsigned*)xw_bf, dinv, convB + (size_t)l * 128,
        (unsigned*)xh_bf, N);
    k_gru<<<gw8, 512, 0, stream>>>(xh_bf, h, h, Bi, Bh, bih, bhh, N);
  }
  // 20) out = h @ fcW + fcB (fp32)
  dim3 g40(1, (N + 63) / 64);
  k_gemm128<false, true><<<g40, 256, 0, stream>>>(h, fcW, fcB, (float*)d_out, N, 40);
}

// Round 7
// 888.250 us; speedup vs baseline: 1.3292x; 1.1059x over previous
//
#include <hip/hip_runtime.h>
#include <hip/hip_bf16.h>
#include <math.h>

typedef __attribute__((ext_vector_type(8))) short bf8_t;   // 8 x bf16 (4 VGPRs)
typedef __attribute__((ext_vector_type(4))) float f4_t;    // MFMA accumulator
typedef __attribute__((ext_vector_type(8))) unsigned short us8_t;

__device__ inline unsigned short f2bf(float f) {
  union { float f; unsigned u; } x; x.f = f;
  unsigned r = x.u + 0x7FFF + ((x.u >> 16) & 1);   // RNE
  return (unsigned short)(r >> 16);
}
__device__ inline float bflo(unsigned v) {
  union { unsigned u; float f; } x; x.u = v << 16; return x.f;
}
__device__ inline float bfhi(unsigned v) {
  union { unsigned u; float f; } x; x.u = v & 0xFFFF0000u; return x.f;
}
__device__ inline float fast_sig(float x) {
  return __builtin_amdgcn_rcpf(1.f + __expf(-x));
}
__device__ inline float fast_tanh(float x) {
  return 1.f - 2.f * __builtin_amdgcn_rcpf(1.f + __expf(2.f * x));
}

// async global->LDS copy, 16B per lane; LDS dest = base + lane*16 (HW rule)
__device__ inline void async_copy16(const void* g, void* l) {
  __builtin_amdgcn_global_load_lds(
      (const __attribute__((address_space(1))) unsigned int*)g,
      (__attribute__((address_space(3))) unsigned int*)l, 16, 0, 0);
}

__device__ inline bf8_t pack_bf8(const float* p) {
  float4 a = *(const float4*)p;
  float4 b = *(const float4*)(p + 4);
  bf8_t t;
  t[0] = (short)f2bf(a.x); t[1] = (short)f2bf(a.y);
  t[2] = (short)f2bf(a.z); t[3] = (short)f2bf(a.w);
  t[4] = (short)f2bf(b.x); t[5] = (short)f2bf(b.y);
  t[6] = (short)f2bf(b.z); t[7] = (short)f2bf(b.w);
  return t;
}

// ---------------------------------------------------------------------------
// device bodies
// ---------------------------------------------------------------------------

// pack weight matrix into MFMA B-fragment order (16x16x32 bf16).
__device__ inline void packB_body(const float* __restrict__ W,
                                  unsigned short* __restrict__ out,
                                  int K, int Ncols, int ldw, int trans, int bid) {
  int idx = bid * 256 + threadIdx.x;
  int total = (Ncols / 16) * (K / 32) * 64;
  if (idx >= total) return;
  int lane = idx & 63;
  int frag = idx >> 6;
  int kt = K / 32;
  int k0 = frag % kt;
  int n0 = frag / kt;
  int n = n0 * 16 + (lane & 15);
  int kbase = k0 * 32 + (lane >> 4) * 8;
  us8_t v;
#pragma unroll
  for (int j = 0; j < 8; ++j) {
    int k = kbase + j;
    float f = trans ? W[(size_t)n * ldw + k] : W[(size_t)k * ldw + n];
    v[j] = f2bf(f);
  }
  *(us8_t*)(out + (size_t)idx * 8) = v;
}

// MFMA GEMM body, 4 waves x 16 rows = 64 rows/block; 32KB smem.
// F32A: A is fp32, converted to bf16 in-register at load.
template<bool RELU, bool BIAS, bool F32A>
__device__ inline void gemm_body4(const void* __restrict__ Araw,
                                  const unsigned short* __restrict__ Bp,
                                  const float* __restrict__ bias,
                                  unsigned short* __restrict__ C, int M, int bid,
                                  unsigned char* smem) {
  int wave = threadIdx.x >> 6, lane = threadIdx.x & 63;
  int row0 = (bid * 4 + wave) * 16;
  int m = lane & 15, q = lane >> 4;

#pragma unroll
  for (int i = 0; i < 8; ++i) {
    int f = wave * 8 + i;
    async_copy16((const unsigned char*)Bp + (size_t)f * 1024 + lane * 16,
                 smem + f * 1024);
  }
  __syncthreads();
  if (row0 >= M) return;

  int arow = row0 + m; if (arow >= M) arow = M - 1;
  bf8_t a[4];
#pragma unroll
  for (int k0 = 0; k0 < 4; ++k0) {
    if (F32A) {
      a[k0] = pack_bf8((const float*)Araw + (size_t)arow * 128 + k0 * 32 + q * 8);
    } else {
      a[k0] = *(const bf8_t*)((const unsigned short*)Araw +
                              (size_t)arow * 128 + k0 * 32 + q * 8);
    }
  }

#pragma unroll
  for (int n0 = 0; n0 < 8; ++n0) {
    f4_t acc = {};
#pragma unroll
    for (int k0 = 0; k0 < 4; ++k0) {
      bf8_t b = *(const bf8_t*)(smem + (n0 * 4 + k0) * 1024 + lane * 16);
      acc = __builtin_amdgcn_mfma_f32_16x16x32_bf16(a[k0], b, acc, 0, 0, 0);
    }
    int col = n0 * 16 + m;
    float bs = BIAS ? bias[col] : 0.f;
#pragma unroll
    for (int r = 0; r < 4; ++r) {
      int grow = row0 + q * 4 + r;
      if (grow < M) {
        float v = acc[r] + bs;
        if (RELU) v = fmaxf(v, 0.f);
        C[(size_t)grow * 128 + col] = f2bf(v);
      }
    }
  }
}

// GRU B-staging, 4 waves: wave stages 6 of 24 frags into one 24KB half
__device__ inline void gru_stage4(const unsigned short* __restrict__ Bi,
                                  const unsigned short* __restrict__ Bh,
                                  unsigned char* half, int wave, int lane, int g) {
#pragma unroll
  for (int s = 0; s < 6; ++s) {
    int cc = g + 8 * (s >= 3 ? s - 3 : s);
    const unsigned short* src = (s < 3) ? Bi : Bh;
    int f = s * 4 + wave;
    async_copy16((const unsigned char*)src + ((size_t)(cc * 4 + wave)) * 1024 + lane * 16,
                 half + f * 1024);
  }
}

// GRU core, 4 waves, DOUBLE-BUFFERED staging (smem = 2 x 24KB).
// Caller issued gru_stage4(g=0 -> half 0). One barrier per group: at the top
// of group g it drains stage(g) (issued a full group earlier -> latency
// hidden); stage(g+1) into the other half is issued right after.
// In-place h safe: each wave touches only its own 16 rows; lookahead reads
// cols of g+1 before writing cols of g. Fully unrolled -> static indices.
__device__ inline void gru_core4(const bf8_t* ax, const float* h_in, float* h_out,
                                 const unsigned short* __restrict__ Bi,
                                 const unsigned short* __restrict__ Bh,
                                 const float* __restrict__ bih, const float* __restrict__ bhh,
                                 int M, int row0, int wave, int lane,
                                 unsigned char* smem) {
  int m = lane & 15, q = lane >> 4;
  int arow = row0 + m; if (arow >= M) arow = M - 1;

  bf8_t ah[4];
#pragma unroll
  for (int k0 = 0; k0 < 4; ++k0)
    ah[k0] = pack_bf8(h_in + (size_t)arow * 128 + k0 * 32 + q * 8);

  // per-thread epilogue rows (clamped for loads; stores guarded by grow<M)
  int erow[4];
#pragma unroll
  for (int r = 0; r < 4; ++r) {
    int gr = row0 + q * 4 + r;
    erow[r] = (gr < M) ? gr : (M - 1);
  }

  // hprev lookahead: group 0 upfront, group g+1 issued during group g
  float hp_cur[4], hp_nxt[4];
#pragma unroll
  for (int r = 0; r < 4; ++r)
    hp_cur[r] = h_in[(size_t)erow[r] * 128 + m];

#pragma unroll
  for (int g = 0; g < 8; ++g) {
    __syncthreads();   // stage(g) complete; prev group's LDS reads all done
    if (g < 7)         // issue next stage NOW -> hides under MFMA + epilogue
      gru_stage4(Bi, Bh, smem + ((g + 1) & 1) * (24 * 1024), wave, lane, g + 1);
    unsigned char* cur = smem + (g & 1) * (24 * 1024);

    f4_t air = {}, aiz = {}, ain = {}, ahr = {}, ahz = {}, ahn = {};
#pragma unroll
    for (int k0 = 0; k0 < 4; ++k0) {
      bf8_t br = *(const bf8_t*)(cur + (0 * 4 + k0) * 1024 + lane * 16);
      bf8_t bz = *(const bf8_t*)(cur + (1 * 4 + k0) * 1024 + lane * 16);
      bf8_t bn = *(const bf8_t*)(cur + (2 * 4 + k0) * 1024 + lane * 16);
      bf8_t cr = *(const bf8_t*)(cur + (3 * 4 + k0) * 1024 + lane * 16);
      bf8_t cz = *(const bf8_t*)(cur + (4 * 4 + k0) * 1024 + lane * 16);
      bf8_t cn = *(const bf8_t*)(cur + (5 * 4 + k0) * 1024 + lane * 16);
      air = __builtin_amdgcn_mfma_f32_16x16x32_bf16(ax[k0], br, air, 0, 0, 0);
      aiz = __builtin_amdgcn_mfma_f32_16x16x32_bf16(ax[k0], bz, aiz, 0, 0, 0);
      ain = __builtin_amdgcn_mfma_f32_16x16x32_bf16(ax[k0], bn, ain, 0, 0, 0);
      ahr = __builtin_amdgcn_mfma_f32_16x16x32_bf16(ah[k0], cr, ahr, 0, 0, 0);
      ahz = __builtin_amdgcn_mfma_f32_16x16x32_bf16(ah[k0], cz, ahz, 0, 0, 0);
      ahn = __builtin_amdgcn_mfma_f32_16x16x32_bf16(ah[k0], cn, ahn, 0, 0, 0);
    }
    if (g < 7) {                         // issue next group's hprev loads
#pragma unroll
      for (int r = 0; r < 4; ++r)
        hp_nxt[r] = h_in[(size_t)erow[r] * 128 + (g + 1) * 16 + m];
    }

    int col = g * 16 + m;
    float bir_ = bih[col], biz_ = bih[col + 128], bin_ = bih[col + 256];
    float bhr_ = bhh[col], bhz_ = bhh[col + 128], bhn_ = bhh[col + 256];
#pragma unroll
    for (int r = 0; r < 4; ++r) {
      int grow = row0 + q * 4 + r;
      if (grow < M) {
        float rr = fast_sig(air[r] + bir_ + ahr[r] + bhr_);
        float zz = fast_sig(aiz[r] + biz_ + ahz[r] + bhz_);
        float nn = fast_tanh(ain[r] + bin_ + rr * (ahn[r] + bhn_));
        h_out[(size_t)grow * 128 + col] = (1.f - zz) * nn + zz * hp_cur[r];
      }
    }
#pragma unroll
    for (int r = 0; r < 4; ++r) hp_cur[r] = hp_nxt[r];
  }
}

// ---------------------------------------------------------------------------
// kernels
// ---------------------------------------------------------------------------

// prep: all 6 weight packs + zero cnt, one launch (256 thr)
__global__ __launch_bounds__(256) void k_prep(
    const float* __restrict__ linW, const float* __restrict__ convW,
    const float* __restrict__ Wih, const float* __restrict__ Whh,
    unsigned short* __restrict__ linWp, unsigned short* __restrict__ convWp,
    unsigned short* __restrict__ Bi, unsigned short* __restrict__ Bh,
    int* __restrict__ cnt, int N) {
  int b = blockIdx.x;
  if (b < 8)  { packB_body(linW, linWp, 128, 128, 128, 0, b); return; }
  if (b < 32) { int l = (b - 8) >> 3;
                packB_body(convW + (size_t)l * 16384, convWp + (size_t)l * 16384,
                           128, 128, 128, 0, (b - 8) & 7); return; }
  if (b < 56) { packB_body(Wih, Bi, 128, 384, 128, 1, b - 32); return; }
  if (b < 80) { packB_body(Whh, Bh, 128, 384, 128, 1, b - 56); return; }
  int i = (b - 80) * 256 + threadIdx.x;
  if (i < N) cnt[i] = 0;
}

// fused: atomic histogram+pos (blocks [0,nCnt)) || lin GEMM from fp32 x
// (rest). Histogram is atomic-pipe bound; GEMM streams x + writes xh —
// no shared cache-sensitive state (R6 evidence: f2bf stream alongside
// count was free). x_bf is never materialized.
__global__ __launch_bounds__(256) void k_count_lin(
    const int* __restrict__ dst, int* __restrict__ cnt, int* __restrict__ pos, int E,
    const float* __restrict__ x, const unsigned short* __restrict__ linWp,
    const float* __restrict__ linB, unsigned short* __restrict__ xh, int M,
    int nCnt) {
  __shared__ unsigned char smem[32 * 1024];
  if ((int)blockIdx.x < nCnt) {
    int e = blockIdx.x * 256 + threadIdx.x;
    if (e < E) pos[e] = atomicAdd(&cnt[dst[e]], 1);
    return;
  }
  gemm_body4<true, true, true>(x, linWp, linB, xh, M, blockIdx.x - nCnt, smem);
}

// hierarchical scan for rowptr
__global__ __launch_bounds__(256) void k_scan_block(
    const int* __restrict__ cnt, int* __restrict__ partial,
    int* __restrict__ bsum, int n) {
  __shared__ int s[256];
  int tid = threadIdx.x;
  int i = blockIdx.x * 256 + tid;
  s[tid] = (i < n) ? cnt[i] : 0;
  __syncthreads();
#pragma unroll
  for (int d = 1; d < 256; d <<= 1) {
    int t = (tid >= d) ? s[tid - d] : 0;
    __syncthreads();
    s[tid] += t;
    __syncthreads();
  }
  if (i < n) partial[i] = s[tid];
  if (tid == 255) bsum[blockIdx.x] = s[255];
}

__global__ __launch_bounds__(512) void k_scan_sums(int* __restrict__ bsum, int nb) {
  __shared__ int s[512];
  int tid = threadIdx.x;
  s[tid] = (tid < nb) ? bsum[tid] : 0;
  __syncthreads();
#pragma unroll
  for (int d = 1; d < 512; d <<= 1) {
    int t = (tid >= d) ? s[tid - d] : 0;
    __syncthreads();
    s[tid] += t;
    __syncthreads();
  }
  if (tid < nb) bsum[tid] = s[tid];
}

__global__ __launch_bounds__(256) void k_scan_add(
    const int* __restrict__ partial, const int* __restrict__ bsum,
    int* __restrict__ rowptr, int n) {
  int i = blockIdx.x * 256 + threadIdx.x;
  if (i == 0) rowptr[0] = 0;
  if (i < n) {
    int v = partial[i] + (blockIdx.x > 0 ? bsum[blockIdx.x - 1] : 0);
    rowptr[i + 1] = v;
  }
}

// atomic-free CSR fill (slot from pos[]), raw weight, NT store (512 thr)
__global__ __launch_bounds__(512) void k_fill(
    const int* __restrict__ src, const int* __restrict__ dst,
    const float* __restrict__ ew, const int* __restrict__ rowptr,
    const int* __restrict__ pos, int2* __restrict__ csr, int E) {
  int e = blockIdx.x * 512 + threadIdx.x;
  if (e >= E) return;
  int d = dst[e];
  int p = rowptr[d] + pos[e];
  unsigned long long v = (unsigned long long)(unsigned)src[e] |
                         ((unsigned long long)(unsigned)__float_as_int(ew[e]) << 32);
  __builtin_nontemporal_store(v, (unsigned long long*)(csr + p));
}

// deg[n] = 1 + sum raw incoming ew; dinv = rsqrt (512 thr)
__global__ __launch_bounds__(512) void k_deg(
    const int* __restrict__ rowptr, const int2* __restrict__ csr,
    float* __restrict__ dinv, int N) {
  int n = blockIdx.x * 512 + threadIdx.x;
  if (n >= N) return;
  int b = rowptr[n], e = rowptr[n + 1];
  float s = 1.0f;
  for (int j = b; j < e; ++j) {
    unsigned long long v = __builtin_nontemporal_load((const unsigned long long*)(csr + j));
    s += __int_as_float((int)(v >> 32));
  }
  dinv[n] = rsqrtf(s);
}

// in-place normalize: w = dinv[src] * ew_raw * dinv[dst] (512 thr)
__global__ __launch_bounds__(512) void k_norm(
    const int* __restrict__ rowptr, int2* __restrict__ csr,
    const float* __restrict__ dinv, int N) {
  int n = blockIdx.x * 512 + threadIdx.x;
  if (n >= N) return;
  int b = rowptr[n], e = rowptr[n + 1];
  float dn = dinv[n];
  for (int j = b; j < e; ++j) {
    unsigned long long v = __builtin_nontemporal_load((const unsigned long long*)(csr + j));
    int s = (int)v;
    float w = dinv[s] * __int_as_float((int)(v >> 32)) * dn;
    unsigned long long nv = (unsigned long long)(unsigned)s |
                            ((unsigned long long)(unsigned)__float_as_int(w) << 32);
    __builtin_nontemporal_store(nv, (unsigned long long*)(csr + j));
  }
}

// conv GEMM (bf16 A), 4 waves / 256 thr
__global__ __launch_bounds__(256) void k_conv(
    const unsigned short* __restrict__ A, const unsigned short* __restrict__ Bp,
    unsigned short* __restrict__ C, int M) {
  __shared__ unsigned char smem[32 * 1024];
  gemm_body4<false, false, false>(A, Bp, nullptr, C, M, blockIdx.x, smem);
}

// GRU, 4 waves / 256 thr, double-buffered staging (48KB -> 3 blocks/CU)
__global__ __launch_bounds__(256, 3) void k_gru(
    const unsigned short* __restrict__ xh, const float* h_in, float* h_out,
    const unsigned short* __restrict__ Bi, const unsigned short* __restrict__ Bh,
    const float* __restrict__ bih, const float* __restrict__ bhh, int M) {
  __shared__ unsigned char smem[2 * 24 * 1024];
  int wave = threadIdx.x >> 6, lane = threadIdx.x & 63;
  int row0 = (blockIdx.x * 4 + wave) * 16;
  gru_stage4(Bi, Bh, smem, wave, lane, 0);
  int m = lane & 15, q = lane >> 4;
  int arow = row0 + m; if (arow >= M) arow = M - 1;
  bf8_t ax[4];
#pragma unroll
  for (int k0 = 0; k0 < 4; ++k0)
    ax[k0] = *(const bf8_t*)(xh + (size_t)arow * 128 + k0 * 32 + q * 8);
  gru_core4(ax, h_in, h_out, Bi, Bh, bih, bhh, M, row0, wave, lane, smem);
}

// ---------------------------------------------------------------------------
// CSR gather aggregation: 1 node per wave (max TLP), 4 waves/block (256 thr).
// NT loads on the streamed CSR protect L2 for the random xw gathers.
// ---------------------------------------------------------------------------

__global__ __launch_bounds__(256) void k_gather(
    const int* __restrict__ rowptr, const int2* __restrict__ csr,
    const unsigned* __restrict__ xw,   // [N,64] packed bf16x2
    const float* __restrict__ dinv, const float* __restrict__ bias,
    unsigned* __restrict__ out, int N) {
  int wave = threadIdx.x >> 6;
  int lane = threadIdx.x & 63;
  int node = __builtin_amdgcn_readfirstlane(blockIdx.x * 4 + wave);
  if (node >= N) return;
  int beg = __builtin_amdgcn_readfirstlane(rowptr[node]);
  int end = __builtin_amdgcn_readfirstlane(rowptr[node + 1]);

  float accl = 0.f, acch = 0.f;
  int k = beg;
  for (; k + 4 <= end; k += 4) {
    unsigned long long r0 = __builtin_nontemporal_load((const unsigned long long*)(csr + k));
    unsigned long long r1 = __builtin_nontemporal_load((const unsigned long long*)(csr + k + 1));
    unsigned long long r2 = __builtin_nontemporal_load((const unsigned long long*)(csr + k + 2));
    unsigned long long r3 = __builtin_nontemporal_load((const unsigned long long*)(csr + k + 3));
    unsigned v0 = xw[((size_t)(unsigned)r0 << 6) + lane];
    unsigned v1 = xw[((size_t)(unsigned)r1 << 6) + lane];
    unsigned v2 = xw[((size_t)(unsigned)r2 << 6) + lane];
    unsigned v3 = xw[((size_t)(unsigned)r3 << 6) + lane];
    float w0 = __int_as_float((int)(r0 >> 32)), w1 = __int_as_float((int)(r1 >> 32));
    float w2 = __int_as_float((int)(r2 >> 32)), w3 = __int_as_float((int)(r3 >> 32));
    accl += bflo(v0) * w0; acch += bfhi(v0) * w0;
    accl += bflo(v1) * w1; acch += bfhi(v1) * w1;
    accl += bflo(v2) * w2; acch += bfhi(v2) * w2;
    accl += bflo(v3) * w3; acch += bfhi(v3) * w3;
  }
  for (; k < end; ++k) {
    unsigned long long r = __builtin_nontemporal_load((const unsigned long long*)(csr + k));
    unsigned v = xw[((size_t)(unsigned)r << 6) + lane];
    float w = __int_as_float((int)(r >> 32));
    accl += bflo(v) * w; acch += bfhi(v) * w;
  }

  float di = dinv[node];
  float sn = di * di;
  unsigned vs = xw[((size_t)node << 6) + lane];
  float2 b = *(const float2*)(bias + lane * 2);
  float rl = fmaxf(accl + bflo(vs) * sn + b.x, 0.f);
  float rh = fmaxf(acch + bfhi(vs) * sn + b.y, 0.f);
  unsigned o = (unsigned)f2bf(rl) | ((unsigned)f2bf(rh) << 16);
  out[((size_t)node << 6) + lane] = o;
}

// ---------------------------------------------------------------------------
// fp32 GEMM (final fc layer)
// ---------------------------------------------------------------------------

template<bool RELU, bool BIAS>
__global__ __launch_bounds__(256) void k_gemm128(
    const float* __restrict__ A, const float* __restrict__ B,
    const float* __restrict__ bias, float* __restrict__ C, int M, int Nc) {
  __shared__ float As[64][36];
  __shared__ float Bs[32][64];
  int tid = threadIdx.x;
  int tx = tid & 15, ty = tid >> 4;
  int row0 = blockIdx.y * 64, col0 = blockIdx.x * 64;
  float acc[4][4] = {};

  for (int k0 = 0; k0 < 128; k0 += 32) {
#pragma unroll
    for (int i = 0; i < 2; ++i) {
      int f = tid + i * 256;
      int r = f >> 3, c4 = f & 7;
      int gr = row0 + r;
      float4 v = make_float4(0.f, 0.f, 0.f, 0.f);
      if (gr < M) v = *(const float4*)(A + (size_t)gr * 128 + k0 + c4 * 4);
      *(float4*)(&As[r][c4 * 4]) = v;
    }
#pragma unroll
    for (int i = 0; i < 2; ++i) {
      int f = tid + i * 256;
      int r = f >> 4, c4 = f & 15;
      int gc = col0 + c4 * 4;
      float4 v = make_float4(0.f, 0.f, 0.f, 0.f);
      if (gc + 3 < Nc) v = *(const float4*)(B + (size_t)(k0 + r) * Nc + gc);
      *(float4*)(&Bs[r][c4 * 4]) = v;
    }
    __syncthreads();
#pragma unroll
    for (int kk = 0; kk < 32; ++kk) {
      float4 b = *(float4*)(&Bs[kk][tx * 4]);
      float a0 = As[ty * 4 + 0][kk];
      float a1 = As[ty * 4 + 1][kk];
      float a2 = As[ty * 4 + 2][kk];
      float a3 = As[ty * 4 + 3][kk];
      acc[0][0] += a0 * b.x; acc[0][1] += a0 * b.y; acc[0][2] += a0 * b.z; acc[0][3] += a0 * b.w;
      acc[1][0] += a1 * b.x; acc[1][1] += a1 * b.y; acc[1][2] += a1 * b.z; acc[1][3] += a1 * b.w;
      acc[2][0] += a2 * b.x; acc[2][1] += a2 * b.y; acc[2][2] += a2 * b.z; acc[2][3] += a2 * b.w;
      acc[3][0] += a3 * b.x; acc[3][1] += a3 * b.y; acc[3][2] += a3 * b.z; acc[3][3] += a3 * b.w;
    }
    __syncthreads();
  }

#pragma unroll
  for (int i = 0; i < 4; ++i) {
    int gr = row0 + ty * 4 + i;
    if (gr >= M) continue;
#pragma unroll
    for (int j = 0; j < 4; ++j) {
      int gc = col0 + tx * 4 + j;
      if (gc >= Nc) continue;
      float v = acc[i][j];
      if (BIAS) v += bias[gc];
      if (RELU) v = fmaxf(v, 0.f);
      C[(size_t)gr * Nc + gc] = v;
    }
  }
}

// ---------------------------------------------------------------------------

extern "C" void kernel_launch(void* const* d_in, const int* in_sizes, int n_in,
                              void* d_out, int out_size, void* d_ws, size_t ws_size,
                              hipStream_t stream) {
  const float* x    = (const float*)d_in[0];
  const int*   ei   = (const int*)d_in[1];
  const float* ew   = (const float*)d_in[2];
  const float* h0   = (const float*)d_in[3];
  const float* linW = (const float*)d_in[4];
  const float* linB = (const float*)d_in[5];
  const float* convW= (const float*)d_in[6];
  const float* convB= (const float*)d_in[7];
  const float* Wih  = (const float*)d_in[8];
  const float* Whh  = (const float*)d_in[9];
  const float* bih  = (const float*)d_in[10];
  const float* bhh  = (const float*)d_in[11];
  const float* fcW  = (const float*)d_in[12];
  const float* fcB  = (const float*)d_in[13];

  int N = in_sizes[0] / 128;
  int E = in_sizes[1] / 2;
  const int* srcI = ei;
  const int* dstI = ei + E;
  int nb = (N + 255) / 256;

  // ---- workspace layout ----
  float* ws = (float*)d_ws;
  size_t off = 0;
  float* dinv = ws + off; off += (size_t)N;
  if (off & 1) off++;                       // 8B-align what follows
  float* h    = ws + off; off += (size_t)N * 128;
  int* iws = (int*)(ws + off);              // 8B-aligned
  size_t ioff = 0;
  int2* csr    = (int2*)iws; ioff += (size_t)2 * E;
  int* cnt     = iws + ioff; ioff += (size_t)N;
  int* partial = iws + ioff; ioff += (size_t)N;
  int* bsum    = iws + ioff; ioff += 512;
  int* rowptr  = iws + ioff; ioff += (size_t)N + 1;
  ioff = (ioff + 3) & ~(size_t)3;           // 16B-align ushort area
  unsigned short* usws = (unsigned short*)(iws + ioff);
  size_t uoff = 0;
  unsigned short* xh_bf  = usws + uoff; uoff += (size_t)N * 128;
  unsigned short* xw_bf  = usws + uoff; uoff += (size_t)N * 128;
  unsigned short* linWp  = usws + uoff; uoff += 128 * 128;
  unsigned short* convWp = usws + uoff; uoff += 3 * 128 * 128;
  unsigned short* Bi     = usws + uoff; uoff += 384 * 128;
  unsigned short* Bh     = usws + uoff; uoff += 384 * 128;

  // pos[E] aliases xw_bf (pos dies at k_fill; xw first written by conv0)
  int* pos = (int*)xw_bf;

  int gw4  = (N + 63) / 64;         // 4 waves x 16 rows per block
  int nCnt = (E + 255) / 256;
  int n512 = (N + 511) / 512;
  int e512 = (E + 511) / 512;
  int ggat = (N + 3) / 4;           // 1 node/wave, 4 waves/block

  // 1) packs + zero cnt
  k_prep<<<80 + nb, 256, 0, stream>>>(linW, convW, Wih, Whh,
                                      linWp, convWp, Bi, Bh, cnt, N);
  // 2) count+pos || xh = relu(x@linW + linB)  (fp32 A converted in-register)
  k_count_lin<<<nCnt + gw4, 256, 0, stream>>>(dstI, cnt, pos, E,
                                              x, linWp, linB, xh_bf, N, nCnt);
  // 3-5) rowptr scan
  k_scan_block<<<nb, 256, 0, stream>>>(cnt, partial, bsum, N);
  k_scan_sums<<<1, 512, 0, stream>>>(bsum, nb);
  k_scan_add<<<nb, 256, 0, stream>>>(partial, bsum, rowptr, N);
  // 6) csr fill (atomic-free)
  k_fill<<<e512, 512, 0, stream>>>(srcI, dstI, ew, rowptr, pos, csr, E);
  // 7) deg/dinv
  k_deg<<<n512, 512, 0, stream>>>(rowptr, csr, dinv, N);
  // 8) normalize csr weights
  k_norm<<<n512, 512, 0, stream>>>(rowptr, csr, dinv, N);
  // 9) GRU#1 (h0 -> h)
  k_gru<<<gw4, 256, 0, stream>>>(xh_bf, h0, h, Bi, Bh, bih, bhh, N);
  // 10-18) 3x { conv, gather, GRU }
  for (int l = 0; l < 3; ++l) {
    k_conv<<<gw4, 256, 0, stream>>>(
        xh_bf, convWp + (size_t)l * 128 * 128, xw_bf, N);
    k_gather<<<ggat, 256, 0, stream>>>(
        rowptr, csr, (const unsigned*)xw_bf, dinv, convB + (size_t)l * 128,
        (unsigned*)xh_bf, N);
    k_gru<<<gw4, 256, 0, stream>>>(xh_bf, h, h, Bi, Bh, bih, bhh, N);
  }
  // 19) out = h @ fcW + fcB (fp32)
  dim3 g40(1, (N + 63) / 64);
  k_gemm128<false, true><<<g40, 256, 0, stream>>>(h, fcW, fcB, (float*)d_out, N, 40);
}